// Round 14
// baseline (4546.115 us; speedup 1.0000x reference)
//
#include <hip/hip_runtime.h>

#define B_ 64
#define S_ 512
#define E_ 256
#define U_ 1024
#define V_ 96
#define G3 3072

typedef float f32x4 __attribute__((ext_vector_type(4)));
typedef short bf16x8 __attribute__((ext_vector_type(8)));
typedef unsigned long long u64;

__device__ __forceinline__ unsigned short f2bf(float f){
  union { float f; unsigned u; } v; v.f = f;
  unsigned r = v.u + 0x7fffu + ((v.u >> 16) & 1u);
  return (unsigned short)(r >> 16);
}

// coherent 16B load (2x u64 system-scope relaxed atomics — the PROVEN class)
__device__ __forceinline__ bf16x8 coh_load16(const unsigned short* p){
  union { u64 q[2]; bf16x8 v; } u;
  u.q[0] = __hip_atomic_load((const u64*)p,     __ATOMIC_RELAXED, __HIP_MEMORY_SCOPE_SYSTEM);
  u.q[1] = __hip_atomic_load((const u64*)p + 1, __ATOMIC_RELAXED, __HIP_MEMORY_SCOPE_SYSTEM);
  return u.v;
}

// ---------------- init kernels ----------------

__global__ void k_embed(const int* __restrict__ tok, const float* __restrict__ emb,
                        unsigned short* __restrict__ x){
  int idx = blockIdx.x * 256 + threadIdx.x;
  if (idx >= B_*S_*E_) return;
  int e = idx & (E_-1); int bt = idx >> 8;
  x[idx] = f2bf(emb[tok[bt]*E_ + e]);
}

__global__ void k_hinit(const float* __restrict__ h0f, const float* __restrict__ h0b,
                        unsigned short* __restrict__ hbuf){
  int i = blockIdx.x * 256 + threadIdx.x;
  if (i >= 2*B_*U_) return;
  const float* s = (i < B_*U_) ? h0f : h0b;
  hbuf[i] = f2bf(s[i & (B_*U_-1)]);
}

__global__ void k_bias(const float* __restrict__ bf_, const float* __restrict__ bb_,
                       float* __restrict__ comb, float* __restrict__ bh0, float* __restrict__ bh1){
  int i = blockIdx.x * 256 + threadIdx.x;
  if (i >= 2*G3) return;
  int d = i / G3, c = i % G3;
  const float* b = d ? bb_ : bf_;
  float b0 = b[c], b1 = b[G3 + c];
  if (c < 2048) comb[d*2048 + c] = b0 + b1;
  else { bh0[d*1024 + c - 2048] = b0; bh1[d*1024 + c - 2048] = b1; }
}

__global__ void k_wdt(const float* __restrict__ Wd, unsigned short* __restrict__ wdT){
  int i = blockIdx.x * 256 + threadIdx.x;
  if (i >= V_*2048) return;
  int k = i & 2047, v = i >> 11;
  wdT[i] = f2bf(Wd[k*V_ + v]);
}

// Pre-packed B fragments — EXACT proven layout, UNCHANGED.
__global__ void k_bpack(const float* __restrict__ Uf, const float* __restrict__ Wf,
                        const float* __restrict__ Ub, const float* __restrict__ Wb,
                        unsigned short* __restrict__ bp){
  int fi = blockIdx.x * 256 + threadIdx.x;
  if (fi >= 2*32*4*10*6*64) return;
  int lane = fi & 63;
  int r = fi >> 6;
  int s  = r % 6;  r /= 6;
  int kt = r % 10; r /= 10;
  int w  = r % 4;  r /= 4;
  int ub = r % 32;
  int dir = r / 32;
  int gkt = w*10 + kt;
  int tile = (s < 4) ? s : ((gkt < 32) ? (2 + s) : s);
  int gate = tile >> 1; if (gate > 2) gate = 2;
  int col = gate*1024 + ub*32 + (tile & 1)*16 + (lane & 15);
  const float* Um = dir ? Ub : Uf;
  const float* Wm = dir ? Wb : Wf;
  int k0 = gkt*32 + (lane >> 4)*8;
  unsigned short o[8];
  #pragma unroll
  for (int j = 0; j < 8; j++){
    int k = k0 + j;
    float v = (k < 1024) ? Um[(size_t)k*G3 + col] : Wm[(size_t)(k-1024)*G3 + col];
    o[j] = f2bf(v);
  }
  *(bf16x8*)(bp + (size_t)fi*8) = *(bf16x8*)o;
}

// ---------------- recurrence kernel ----------------
// R13 (2040us PASS) base. SINGLE structural delta: double-buffered lred
// ([2][8][16][132] = 135KB LDS) removes the end-of-step barrier; each
// epilogue wave (w<4) drains ITS OWN h stores (s_waitcnt vmcnt(0) builtin,
// proven R12) and posts flag[ub*4+w] immediately. Waves 4-7 run ahead into
// step t+1 (poll/load/MFMA) while waves 0-3 finish the epilogue.
// Safety: lred[par] WAR at t+2 gated by flag@t+1->poll (consuming waves)
// or barrier1@t+1 arrival (wave 7); flags@t+1 depend only on flags@t ->
// deadlock-free by induction. All cross-block ops = proven atomic class.
__global__ void __launch_bounds__(512, 2)
k_rec(const unsigned short* __restrict__ bp, const unsigned short* __restrict__ x,
      unsigned short* __restrict__ hbuf, unsigned short* __restrict__ hseq,
      const float* __restrict__ comb, const float* __restrict__ bh0, const float* __restrict__ bh1,
      const float* __restrict__ h0f, const float* __restrict__ h0b,
      float* __restrict__ out, int* __restrict__ flags)
{
  __shared__ float lred[2][8][16][132];
  int blk = blockIdx.x;
  int dir = blk >> 7;
  int bg  = (blk >> 5) & 3;
  int ub  = blk & 31;
  int tid = threadIdx.x;
  int w = tid >> 6, lane = tid & 63;
  int w4 = w >> 1, ktbase = (w & 1) * 5;
  int row0 = bg * 16, u0 = ub * 32;
  int* gflag = flags + (dir*4 + bg) * 128;   // [ub*4 + epilogue-wave]

  // B fragments -> registers (30 x dwordx4 per wave), then PIN (no remat)
  bf16x8 bfr[5][6];
  {
    const bf16x8* bpp = (const bf16x8*)bp + ((size_t)((dir*32 + ub)*4 + w4) * 60) * 64 + lane;
    #pragma unroll
    for (int kt = 0; kt < 5; kt++)
      #pragma unroll
      for (int s = 0; s < 6; s++)
        bfr[kt][s] = bpp[((ktbase + kt)*6 + s) * 64];
  }
  #pragma unroll
  for (int kt = 0; kt < 5; kt++)
    #pragma unroll
    for (int s = 0; s < 6; s++)
      asm volatile("" : "+v"(bfr[kt][s]));

  // epilogue constants (tid<256 only). my_r=tid>>4, my_u=(tid&15)*2 (R13)
  int my_r = tid >> 4, my_u = (tid & 15) * 2;
  float hold0=0.f, hold1=0.f, bz0=0.f, bz1=0.f, br0=0.f, br1=0.f;
  float bha0=0.f, bha1=0.f, bhb0=0.f, bhb1=0.f;
  if (tid < 256){
    const float* h0 = dir ? h0b : h0f;
    hold0 = h0[(row0 + my_r)*U_ + u0 + my_u];
    hold1 = h0[(row0 + my_r)*U_ + u0 + my_u + 1];
    bz0 = comb[dir*2048 + u0 + my_u];        bz1 = comb[dir*2048 + u0 + my_u + 1];
    br0 = comb[dir*2048 + 1024 + u0 + my_u]; br1 = comb[dir*2048 + 1024 + u0 + my_u + 1];
    bha0 = bh0[dir*1024 + u0 + my_u]; bha1 = bh0[dir*1024 + u0 + my_u + 1];
    bhb0 = bh1[dir*1024 + u0 + my_u]; bhb1 = bh1[dir*1024 + u0 + my_u + 1];
  }

  const unsigned short* xrow = x + (size_t)(row0 + (lane & 15)) * S_ * E_ + ((lane >> 4) * 8);
  unsigned short* hseq_p = hseq + (size_t)(row0 + my_r) * S_ * 2048 + dir*1024 + u0 + my_u;
  int fl = lane & 31;

  for (int t = 0; t < S_; t++){
    int par = t & 1;
    int tp = dir ? (S_-1 - t) : t;
    f32x4 acc[8];
    #pragma unroll
    for (int i = 0; i < 8; i++) acc[i] = (f32x4){0.f,0.f,0.f,0.f};

    // pre-poll x MFMAs (h-independent): wave6 kt2..4 (gkt 32..34), wave7 kt0..4 (gkt 35..39)
    if (w == 6){
      const unsigned short* xp = xrow + (size_t)tp * E_;
      #pragma unroll
      for (int kt = 2; kt < 5; kt++){
        bf16x8 a = *(const bf16x8*)(xp + (kt - 2)*32);
        acc[0] = __builtin_amdgcn_mfma_f32_16x16x32_bf16(a, bfr[kt][0], acc[0], 0,0,0);
        acc[1] = __builtin_amdgcn_mfma_f32_16x16x32_bf16(a, bfr[kt][1], acc[1], 0,0,0);
        acc[2] = __builtin_amdgcn_mfma_f32_16x16x32_bf16(a, bfr[kt][2], acc[2], 0,0,0);
        acc[3] = __builtin_amdgcn_mfma_f32_16x16x32_bf16(a, bfr[kt][3], acc[3], 0,0,0);
        acc[4] = __builtin_amdgcn_mfma_f32_16x16x32_bf16(a, bfr[kt][4], acc[4], 0,0,0);
        acc[5] = __builtin_amdgcn_mfma_f32_16x16x32_bf16(a, bfr[kt][5], acc[5], 0,0,0);
      }
    } else if (w == 7){
      const unsigned short* xp = xrow + (size_t)tp * E_;
      #pragma unroll
      for (int kt = 0; kt < 5; kt++){
        bf16x8 a = *(const bf16x8*)(xp + 96 + kt*32);
        acc[0] = __builtin_amdgcn_mfma_f32_16x16x32_bf16(a, bfr[kt][0], acc[0], 0,0,0);
        acc[1] = __builtin_amdgcn_mfma_f32_16x16x32_bf16(a, bfr[kt][1], acc[1], 0,0,0);
        acc[2] = __builtin_amdgcn_mfma_f32_16x16x32_bf16(a, bfr[kt][2], acc[2], 0,0,0);
        acc[3] = __builtin_amdgcn_mfma_f32_16x16x32_bf16(a, bfr[kt][3], acc[3], 0,0,0);
        acc[4] = __builtin_amdgcn_mfma_f32_16x16x32_bf16(a, bfr[kt][4], acc[4], 0,0,0);
        acc[5] = __builtin_amdgcn_mfma_f32_16x16x32_bf16(a, bfr[kt][5], acc[5], 0,0,0);
      }
    }

    // poll the group's 128 per-wave flags (2 per lane); wave 7 consumes no h
    if (t > 0 && w < 7){
      const int* f0 = gflag + lane;
      const int* f1 = gflag + 64 + lane;
      while (true){
        int v0 = __hip_atomic_load(f0, __ATOMIC_RELAXED, __HIP_MEMORY_SCOPE_SYSTEM);
        int v1 = __hip_atomic_load(f1, __ATOMIC_RELAXED, __HIP_MEMORY_SCOPE_SYSTEM);
        if (__all((v0 >= t) && (v1 >= t))) break;
      }
      __atomic_signal_fence(__ATOMIC_SEQ_CST);
      __builtin_amdgcn_sched_barrier(0);
    }

    const unsigned short* hb = hbuf + ((size_t)(par*2 + dir) * B_ + row0 + (lane & 15)) * U_ + ((lane >> 4) * 8);
    if (w < 6){
      bf16x8 ha[5];
      #pragma unroll
      for (int kt = 0; kt < 5; kt++) ha[kt] = coh_load16(hb + (w*5 + kt)*32);
      #pragma unroll
      for (int kt = 0; kt < 5; kt++){
        acc[0] = __builtin_amdgcn_mfma_f32_16x16x32_bf16(ha[kt], bfr[kt][0], acc[0], 0,0,0);
        acc[1] = __builtin_amdgcn_mfma_f32_16x16x32_bf16(ha[kt], bfr[kt][1], acc[1], 0,0,0);
        acc[2] = __builtin_amdgcn_mfma_f32_16x16x32_bf16(ha[kt], bfr[kt][2], acc[2], 0,0,0);
        acc[3] = __builtin_amdgcn_mfma_f32_16x16x32_bf16(ha[kt], bfr[kt][3], acc[3], 0,0,0);
        acc[6] = __builtin_amdgcn_mfma_f32_16x16x32_bf16(ha[kt], bfr[kt][4], acc[6], 0,0,0);
        acc[7] = __builtin_amdgcn_mfma_f32_16x16x32_bf16(ha[kt], bfr[kt][5], acc[7], 0,0,0);
      }
    } else if (w == 6){
      bf16x8 ha[2];
      #pragma unroll
      for (int kt = 0; kt < 2; kt++) ha[kt] = coh_load16(hb + (30 + kt)*32);
      #pragma unroll
      for (int kt = 0; kt < 2; kt++){
        acc[0] = __builtin_amdgcn_mfma_f32_16x16x32_bf16(ha[kt], bfr[kt][0], acc[0], 0,0,0);
        acc[1] = __builtin_amdgcn_mfma_f32_16x16x32_bf16(ha[kt], bfr[kt][1], acc[1], 0,0,0);
        acc[2] = __builtin_amdgcn_mfma_f32_16x16x32_bf16(ha[kt], bfr[kt][2], acc[2], 0,0,0);
        acc[3] = __builtin_amdgcn_mfma_f32_16x16x32_bf16(ha[kt], bfr[kt][3], acc[3], 0,0,0);
        acc[6] = __builtin_amdgcn_mfma_f32_16x16x32_bf16(ha[kt], bfr[kt][4], acc[6], 0,0,0);
        acc[7] = __builtin_amdgcn_mfma_f32_16x16x32_bf16(ha[kt], bfr[kt][5], acc[7], 0,0,0);
      }
    }

    // partial sums -> LDS double buffer [par]
    #pragma unroll
    for (int tl = 0; tl < 8; tl++){
      #pragma unroll
      for (int r4 = 0; r4 < 4; r4++)
        lred[par][w][(lane>>4)*4 + r4][tl*16 + (lane & 15)] = acc[tl][r4];
    }
    __syncthreads();   // the ONLY barrier per step: lred[par] complete

    if (tid < 256){
      float sz0=0,sr0=0,sxh0=0,srh0=0, sz1=0,sr1=0,sxh1=0,srh1=0;
      #pragma unroll
      for (int ww = 0; ww < 8; ww++){
        sz0 += lred[par][ww][my_r][my_u];      sz1 += lred[par][ww][my_r][my_u+1];
        sr0 += lred[par][ww][my_r][32+my_u];   sr1 += lred[par][ww][my_r][32+my_u+1];
        sxh0+= lred[par][ww][my_r][64+my_u];   sxh1+= lred[par][ww][my_r][64+my_u+1];
        srh0+= lred[par][ww][my_r][96+my_u];   srh1+= lred[par][ww][my_r][96+my_u+1];
      }
      float z0 = 1.f/(1.f + __expf(-(sz0 + bz0)));
      float z1 = 1.f/(1.f + __expf(-(sz1 + bz1)));
      float rg0 = 1.f/(1.f + __expf(-(sr0 + br0)));
      float rg1 = 1.f/(1.f + __expf(-(sr1 + br1)));
      float c0 = tanhf(sxh0 + bha0 + rg0*(srh0 + bhb0));
      float c1 = tanhf(sxh1 + bha1 + rg1*(srh1 + bhb1));
      float hn0 = z0*hold0 + (1.f - z0)*c0;
      float hn1 = z1*hold1 + (1.f - z1)*c1;
      unsigned pk = (unsigned)f2bf(hn0) | ((unsigned)f2bf(hn1) << 16);
      // coherent h store: 16 lanes x 4B contiguous per row (64B coalesced runs)
      __hip_atomic_store((unsigned*)(hbuf + (((size_t)(par^1)*2 + dir) * B_ + row0 + my_r) * U_ + u0 + my_u),
                         pk, __ATOMIC_RELAXED, __HIP_MEMORY_SCOPE_SYSTEM);
      if (t == S_-1){
        float* o = out + (size_t)B_*S_*V_ + dir*B_*U_ + (row0 + my_r)*U_ + u0 + my_u;
        o[0] = hn0; o[1] = hn1;
      }
      hold0 = hn0; hold1 = hn1;
      // per-wave drain (vmcnt(0) only; no memory clobber) + per-wave flag
      if (t < S_-1){
        __builtin_amdgcn_s_waitcnt(0x0F70);
        if (lane == 0)
          __hip_atomic_store(gflag + ub*4 + w, t + 1, __ATOMIC_RELAXED, __HIP_MEMORY_SCOPE_SYSTEM);
      }
      // hseq store after the signal path (no in-kernel consumer)
      *(unsigned*)(hseq_p + (size_t)tp * 2048) = pk;
    }
  }
}

// ---------------- logits GEMM ----------------
__global__ void __launch_bounds__(256)
k_logits(const unsigned short* __restrict__ hseq, const unsigned short* __restrict__ wdT,
         const float* __restrict__ bd, float* __restrict__ out){
  __shared__ unsigned short As[128][40];
  int tid = threadIdx.x, w = tid >> 6, lane = tid & 63;
  size_t r0 = (size_t)blockIdx.x * 128;
  f32x4 acc[2][6];
  #pragma unroll
  for (int mt=0; mt<2; mt++)
    #pragma unroll
    for (int n=0; n<6; n++) acc[mt][n] = (f32x4){0.f,0.f,0.f,0.f};
  float bdv[6];
  #pragma unroll
  for (int n=0; n<6; n++) bdv[n] = bd[n*16 + (lane & 15)];

  for (int kc = 0; kc < 64; kc++){
    __syncthreads();
    #pragma unroll
    for (int i = 0; i < 2; i++){
      int v = tid*2 + i; int rr = v >> 2, k8 = (v & 3)*8;
      *(bf16x8*)&As[rr][k8] = *(const bf16x8*)(hseq + (r0 + rr)*2048 + kc*32 + k8);
    }
    __syncthreads();
    bf16x8 bfr[6];
    #pragma unroll
    for (int n=0; n<6; n++)
      bfr[n] = *(const bf16x8*)(wdT + (size_t)(n*16 + (lane&15))*2048 + kc*32 + (lane>>4)*8);
    #pragma unroll
    for (int mt=0; mt<2; mt++){
      bf16x8 a = *(const bf16x8*)&As[w*32 + mt*16 + (lane & 15)][(lane >> 4)*8];
      #pragma unroll
      for (int n=0; n<6; n++)
        acc[mt][n] = __builtin_amdgcn_mfma_f32_16x16x32_bf16(a, bfr[n], acc[mt][n], 0,0,0);
    }
  }
  #pragma unroll
  for (int mt=0; mt<2; mt++)
    #pragma unroll
    for (int n=0; n<6; n++)
      #pragma unroll
      for (int r4=0; r4<4; r4++){
        size_t row = r0 + w*32 + mt*16 + (lane>>4)*4 + r4;
        out[row*V_ + n*16 + (lane&15)] = acc[mt][n][r4] + bdv[n];
      }
}

// ---------------- launch ----------------
extern "C" void kernel_launch(void* const* d_in, const int* in_sizes, int n_in,
                              void* d_out, int out_size, void* d_ws, size_t ws_size,
                              hipStream_t stream){
  const int*   tok = (const int*)d_in[0];
  const float* emb = (const float*)d_in[1];
  const float* Wf  = (const float*)d_in[2];
  const float* Uf  = (const float*)d_in[3];
  const float* bf_ = (const float*)d_in[4];
  const float* Wb  = (const float*)d_in[5];
  const float* Ub  = (const float*)d_in[6];
  const float* bb_ = (const float*)d_in[7];
  const float* Wd  = (const float*)d_in[8];
  const float* bd  = (const float*)d_in[9];
  const float* h0f = (const float*)d_in[10];
  const float* h0b = (const float*)d_in[11];

  char* ws = (char*)d_ws;
  size_t off = 0;
  auto alloc = [&](size_t n){ char* p = ws + off; off += (n + 255) & ~(size_t)255; return p; };
  unsigned short* bp   = (unsigned short*)alloc((size_t)2*32*4*10*6*64*16);
  unsigned short* x    = (unsigned short*)alloc((size_t)B_*S_*E_*2);
  unsigned short* hseq = (unsigned short*)alloc((size_t)B_*S_*2048*2);
  unsigned short* hbuf = (unsigned short*)alloc((size_t)2*2*B_*U_*2);
  unsigned short* wdT  = (unsigned short*)alloc((size_t)V_*2048*2);
  float* comb = (float*)alloc((size_t)2*2048*4);
  float* bh0  = (float*)alloc((size_t)2*1024*4);
  float* bh1  = (float*)alloc((size_t)2*1024*4);
  int*   flags= (int*)alloc((size_t)1024*4);   // 8 groups x 128 per-wave flags

  hipMemsetAsync(flags, 0, (size_t)1024*4, stream);
  k_embed<<<(B_*S_*E_+255)/256, 256, 0, stream>>>(tok, emb, x);
  k_hinit<<<(2*B_*U_+255)/256, 256, 0, stream>>>(h0f, h0b, hbuf);
  k_bias <<<(2*G3+255)/256, 256, 0, stream>>>(bf_, bb_, comb, bh0, bh1);
  k_wdt  <<<(V_*2048+255)/256, 256, 0, stream>>>(Wd, wdT);
  k_bpack<<<(2*32*4*10*6*64+255)/256, 256, 0, stream>>>(Uf, Wf, Ub, Wb, bp);
  k_rec  <<<256, 512, 0, stream>>>(bp, x, hbuf, hseq, comb, bh0, bh1, h0f, h0b, (float*)d_out, flags);
  k_logits<<<256, 256, 0, stream>>>(hseq, wdT, bd, (float*)d_out);
}

// Round 15
// 2076.974 us; speedup vs baseline: 2.1888x; 2.1888x over previous
//
#include <hip/hip_runtime.h>

#define B_ 64
#define S_ 512
#define E_ 256
#define U_ 1024
#define V_ 96
#define G3 3072

typedef float f32x4 __attribute__((ext_vector_type(4)));
typedef short bf16x8 __attribute__((ext_vector_type(8)));
typedef unsigned long long u64;

__device__ __forceinline__ unsigned short f2bf(float f){
  union { float f; unsigned u; } v; v.f = f;
  unsigned r = v.u + 0x7fffu + ((v.u >> 16) & 1u);
  return (unsigned short)(r >> 16);
}

// coherent 16B load (2x u64 system-scope relaxed atomics — the PROVEN class)
__device__ __forceinline__ bf16x8 coh_load16(const unsigned short* p){
  union { u64 q[2]; bf16x8 v; } u;
  u.q[0] = __hip_atomic_load((const u64*)p,     __ATOMIC_RELAXED, __HIP_MEMORY_SCOPE_SYSTEM);
  u.q[1] = __hip_atomic_load((const u64*)p + 1, __ATOMIC_RELAXED, __HIP_MEMORY_SCOPE_SYSTEM);
  return u.v;
}

// ---------------- init kernels ----------------

__global__ void k_embed(const int* __restrict__ tok, const float* __restrict__ emb,
                        unsigned short* __restrict__ x){
  int idx = blockIdx.x * 256 + threadIdx.x;
  if (idx >= B_*S_*E_) return;
  int e = idx & (E_-1); int bt = idx >> 8;
  x[idx] = f2bf(emb[tok[bt]*E_ + e]);
}

__global__ void k_hinit(const float* __restrict__ h0f, const float* __restrict__ h0b,
                        unsigned short* __restrict__ hbuf){
  int i = blockIdx.x * 256 + threadIdx.x;
  if (i >= 2*B_*U_) return;
  const float* s = (i < B_*U_) ? h0f : h0b;
  hbuf[i] = f2bf(s[i & (B_*U_-1)]);
}

__global__ void k_bias(const float* __restrict__ bf_, const float* __restrict__ bb_,
                       float* __restrict__ comb, float* __restrict__ bh0, float* __restrict__ bh1){
  int i = blockIdx.x * 256 + threadIdx.x;
  if (i >= 2*G3) return;
  int d = i / G3, c = i % G3;
  const float* b = d ? bb_ : bf_;
  float b0 = b[c], b1 = b[G3 + c];
  if (c < 2048) comb[d*2048 + c] = b0 + b1;
  else { bh0[d*1024 + c - 2048] = b0; bh1[d*1024 + c - 2048] = b1; }
}

__global__ void k_wdt(const float* __restrict__ Wd, unsigned short* __restrict__ wdT){
  int i = blockIdx.x * 256 + threadIdx.x;
  if (i >= V_*2048) return;
  int k = i & 2047, v = i >> 11;
  wdT[i] = f2bf(Wd[k*V_ + v]);
}

// Pre-packed B fragments — EXACT proven layout, UNCHANGED.
__global__ void k_bpack(const float* __restrict__ Uf, const float* __restrict__ Wf,
                        const float* __restrict__ Ub, const float* __restrict__ Wb,
                        unsigned short* __restrict__ bp){
  int fi = blockIdx.x * 256 + threadIdx.x;
  if (fi >= 2*32*4*10*6*64) return;
  int lane = fi & 63;
  int r = fi >> 6;
  int s  = r % 6;  r /= 6;
  int kt = r % 10; r /= 10;
  int w  = r % 4;  r /= 4;
  int ub = r % 32;
  int dir = r / 32;
  int gkt = w*10 + kt;
  int tile = (s < 4) ? s : ((gkt < 32) ? (2 + s) : s);
  int gate = tile >> 1; if (gate > 2) gate = 2;
  int col = gate*1024 + ub*32 + (tile & 1)*16 + (lane & 15);
  const float* Um = dir ? Ub : Uf;
  const float* Wm = dir ? Wb : Wf;
  int k0 = gkt*32 + (lane >> 4)*8;
  unsigned short o[8];
  #pragma unroll
  for (int j = 0; j < 8; j++){
    int k = k0 + j;
    float v = (k < 1024) ? Um[(size_t)k*G3 + col] : Wm[(size_t)(k-1024)*G3 + col];
    o[j] = f2bf(v);
  }
  *(bf16x8*)(bp + (size_t)fi*8) = *(bf16x8*)o;
}

// ---------------- recurrence kernel ----------------
// R13 (2040us PASS) EXACT skeleton: poll 32 block-flags -> coh h loads ->
// MFMA -> lred -> barrier -> gates -> atomic h store -> barrier (drain) ->
// tid0 flag store -> hseq store. Remap my_r=tid>>4, my_u=(tid&15)*2 (R13).
// SINGLE delta vs R13: s_sleep(1) in the poll-miss path. ~12k lanes/group
// hammer one 128B flag region; throttling the spin cuts LLC read pressure
// so the producer's flag store commits/propagates faster (R9/R14 showed
// poll traffic is expensive). Pure delay instr: zero correctness surface.
__global__ void __launch_bounds__(512, 2)
k_rec(const unsigned short* __restrict__ bp, const unsigned short* __restrict__ x,
      unsigned short* __restrict__ hbuf, unsigned short* __restrict__ hseq,
      const float* __restrict__ comb, const float* __restrict__ bh0, const float* __restrict__ bh1,
      const float* __restrict__ h0f, const float* __restrict__ h0b,
      float* __restrict__ out, int* __restrict__ flags)
{
  __shared__ float lred[8][16][132];
  int blk = blockIdx.x;
  int dir = blk >> 7;
  int bg  = (blk >> 5) & 3;
  int ub  = blk & 31;
  int tid = threadIdx.x;
  int w = tid >> 6, lane = tid & 63;
  int w4 = w >> 1, ktbase = (w & 1) * 5;
  int row0 = bg * 16, u0 = ub * 32;
  int* gflag = flags + (dir*4 + bg) * 32;

  // B fragments -> registers (30 x dwordx4 per wave), then PIN (no remat)
  bf16x8 bfr[5][6];
  {
    const bf16x8* bpp = (const bf16x8*)bp + ((size_t)((dir*32 + ub)*4 + w4) * 60) * 64 + lane;
    #pragma unroll
    for (int kt = 0; kt < 5; kt++)
      #pragma unroll
      for (int s = 0; s < 6; s++)
        bfr[kt][s] = bpp[((ktbase + kt)*6 + s) * 64];
  }
  #pragma unroll
  for (int kt = 0; kt < 5; kt++)
    #pragma unroll
    for (int s = 0; s < 6; s++)
      asm volatile("" : "+v"(bfr[kt][s]));

  // epilogue constants (tid<256 only). my_r=tid>>4, my_u=(tid&15)*2 (R13)
  int my_r = tid >> 4, my_u = (tid & 15) * 2;
  float hold0=0.f, hold1=0.f, bz0=0.f, bz1=0.f, br0=0.f, br1=0.f;
  float bha0=0.f, bha1=0.f, bhb0=0.f, bhb1=0.f;
  if (tid < 256){
    const float* h0 = dir ? h0b : h0f;
    hold0 = h0[(row0 + my_r)*U_ + u0 + my_u];
    hold1 = h0[(row0 + my_r)*U_ + u0 + my_u + 1];
    bz0 = comb[dir*2048 + u0 + my_u];        bz1 = comb[dir*2048 + u0 + my_u + 1];
    br0 = comb[dir*2048 + 1024 + u0 + my_u]; br1 = comb[dir*2048 + 1024 + u0 + my_u + 1];
    bha0 = bh0[dir*1024 + u0 + my_u]; bha1 = bh0[dir*1024 + u0 + my_u + 1];
    bhb0 = bh1[dir*1024 + u0 + my_u]; bhb1 = bh1[dir*1024 + u0 + my_u + 1];
  }

  const unsigned short* xrow = x + (size_t)(row0 + (lane & 15)) * S_ * E_ + ((lane >> 4) * 8);
  unsigned short* hseq_p = hseq + (size_t)(row0 + my_r) * S_ * 2048 + dir*1024 + u0 + my_u;
  int fl = lane & 31;

  for (int t = 0; t < S_; t++){
    int par = t & 1;
    int tp = dir ? (S_-1 - t) : t;
    f32x4 acc[8];
    #pragma unroll
    for (int i = 0; i < 8; i++) acc[i] = (f32x4){0.f,0.f,0.f,0.f};

    // pre-poll x MFMAs (h-independent): wave6 kt2..4 (gkt 32..34), wave7 kt0..4 (gkt 35..39)
    if (w == 6){
      const unsigned short* xp = xrow + (size_t)tp * E_;
      #pragma unroll
      for (int kt = 2; kt < 5; kt++){
        bf16x8 a = *(const bf16x8*)(xp + (kt - 2)*32);
        acc[0] = __builtin_amdgcn_mfma_f32_16x16x32_bf16(a, bfr[kt][0], acc[0], 0,0,0);
        acc[1] = __builtin_amdgcn_mfma_f32_16x16x32_bf16(a, bfr[kt][1], acc[1], 0,0,0);
        acc[2] = __builtin_amdgcn_mfma_f32_16x16x32_bf16(a, bfr[kt][2], acc[2], 0,0,0);
        acc[3] = __builtin_amdgcn_mfma_f32_16x16x32_bf16(a, bfr[kt][3], acc[3], 0,0,0);
        acc[4] = __builtin_amdgcn_mfma_f32_16x16x32_bf16(a, bfr[kt][4], acc[4], 0,0,0);
        acc[5] = __builtin_amdgcn_mfma_f32_16x16x32_bf16(a, bfr[kt][5], acc[5], 0,0,0);
      }
    } else if (w == 7){
      const unsigned short* xp = xrow + (size_t)tp * E_;
      #pragma unroll
      for (int kt = 0; kt < 5; kt++){
        bf16x8 a = *(const bf16x8*)(xp + 96 + kt*32);
        acc[0] = __builtin_amdgcn_mfma_f32_16x16x32_bf16(a, bfr[kt][0], acc[0], 0,0,0);
        acc[1] = __builtin_amdgcn_mfma_f32_16x16x32_bf16(a, bfr[kt][1], acc[1], 0,0,0);
        acc[2] = __builtin_amdgcn_mfma_f32_16x16x32_bf16(a, bfr[kt][2], acc[2], 0,0,0);
        acc[3] = __builtin_amdgcn_mfma_f32_16x16x32_bf16(a, bfr[kt][3], acc[3], 0,0,0);
        acc[4] = __builtin_amdgcn_mfma_f32_16x16x32_bf16(a, bfr[kt][4], acc[4], 0,0,0);
        acc[5] = __builtin_amdgcn_mfma_f32_16x16x32_bf16(a, bfr[kt][5], acc[5], 0,0,0);
      }
    }

    // poll the group's 32 block flags; s_sleep(1) on miss throttles the spin
    if (t > 0 && w < 7){
      while (true){
        int v = __hip_atomic_load(gflag + fl, __ATOMIC_RELAXED, __HIP_MEMORY_SCOPE_SYSTEM);
        if (__all(v >= t)) break;
        __builtin_amdgcn_s_sleep(1);
      }
      __atomic_signal_fence(__ATOMIC_SEQ_CST);
      __builtin_amdgcn_sched_barrier(0);
    }

    const unsigned short* hb = hbuf + ((size_t)(par*2 + dir) * B_ + row0 + (lane & 15)) * U_ + ((lane >> 4) * 8);
    if (w < 6){
      bf16x8 ha[5];
      #pragma unroll
      for (int kt = 0; kt < 5; kt++) ha[kt] = coh_load16(hb + (w*5 + kt)*32);
      #pragma unroll
      for (int kt = 0; kt < 5; kt++){
        acc[0] = __builtin_amdgcn_mfma_f32_16x16x32_bf16(ha[kt], bfr[kt][0], acc[0], 0,0,0);
        acc[1] = __builtin_amdgcn_mfma_f32_16x16x32_bf16(ha[kt], bfr[kt][1], acc[1], 0,0,0);
        acc[2] = __builtin_amdgcn_mfma_f32_16x16x32_bf16(ha[kt], bfr[kt][2], acc[2], 0,0,0);
        acc[3] = __builtin_amdgcn_mfma_f32_16x16x32_bf16(ha[kt], bfr[kt][3], acc[3], 0,0,0);
        acc[6] = __builtin_amdgcn_mfma_f32_16x16x32_bf16(ha[kt], bfr[kt][4], acc[6], 0,0,0);
        acc[7] = __builtin_amdgcn_mfma_f32_16x16x32_bf16(ha[kt], bfr[kt][5], acc[7], 0,0,0);
      }
    } else if (w == 6){
      bf16x8 ha[2];
      #pragma unroll
      for (int kt = 0; kt < 2; kt++) ha[kt] = coh_load16(hb + (30 + kt)*32);
      #pragma unroll
      for (int kt = 0; kt < 2; kt++){
        acc[0] = __builtin_amdgcn_mfma_f32_16x16x32_bf16(ha[kt], bfr[kt][0], acc[0], 0,0,0);
        acc[1] = __builtin_amdgcn_mfma_f32_16x16x32_bf16(ha[kt], bfr[kt][1], acc[1], 0,0,0);
        acc[2] = __builtin_amdgcn_mfma_f32_16x16x32_bf16(ha[kt], bfr[kt][2], acc[2], 0,0,0);
        acc[3] = __builtin_amdgcn_mfma_f32_16x16x32_bf16(ha[kt], bfr[kt][3], acc[3], 0,0,0);
        acc[6] = __builtin_amdgcn_mfma_f32_16x16x32_bf16(ha[kt], bfr[kt][4], acc[6], 0,0,0);
        acc[7] = __builtin_amdgcn_mfma_f32_16x16x32_bf16(ha[kt], bfr[kt][5], acc[7], 0,0,0);
      }
    }

    // partial sums -> LDS (C layout: col = lane&15, row = (lane>>4)*4 + r)
    #pragma unroll
    for (int tl = 0; tl < 8; tl++){
      #pragma unroll
      for (int r4 = 0; r4 < 4; r4++)
        lred[w][(lane>>4)*4 + r4][tl*16 + (lane & 15)] = acc[tl][r4];
    }
    __syncthreads();

    unsigned pk = 0;
    if (tid < 256){
      float sz0=0,sr0=0,sxh0=0,srh0=0, sz1=0,sr1=0,sxh1=0,srh1=0;
      #pragma unroll
      for (int ww = 0; ww < 8; ww++){
        sz0 += lred[ww][my_r][my_u];      sz1 += lred[ww][my_r][my_u+1];
        sr0 += lred[ww][my_r][32+my_u];   sr1 += lred[ww][my_r][32+my_u+1];
        sxh0+= lred[ww][my_r][64+my_u];   sxh1+= lred[ww][my_r][64+my_u+1];
        srh0+= lred[ww][my_r][96+my_u];   srh1+= lred[ww][my_r][96+my_u+1];
      }
      float z0 = 1.f/(1.f + __expf(-(sz0 + bz0)));
      float z1 = 1.f/(1.f + __expf(-(sz1 + bz1)));
      float rg0 = 1.f/(1.f + __expf(-(sr0 + br0)));
      float rg1 = 1.f/(1.f + __expf(-(sr1 + br1)));
      float c0 = tanhf(sxh0 + bha0 + rg0*(srh0 + bhb0));
      float c1 = tanhf(sxh1 + bha1 + rg1*(srh1 + bhb1));
      float hn0 = z0*hold0 + (1.f - z0)*c0;
      float hn1 = z1*hold1 + (1.f - z1)*c1;
      pk = (unsigned)f2bf(hn0) | ((unsigned)f2bf(hn1) << 16);
      // coherent h store: 16 lanes x 4B contiguous per row (64B coalesced runs)
      __hip_atomic_store((unsigned*)(hbuf + (((size_t)(par^1)*2 + dir) * B_ + row0 + my_r) * U_ + u0 + my_u),
                         pk, __ATOMIC_RELAXED, __HIP_MEMORY_SCOPE_SYSTEM);
      if (t == S_-1){
        float* o = out + (size_t)B_*S_*V_ + dir*B_*U_ + (row0 + my_r)*U_ + u0 + my_u;
        o[0] = hn0; o[1] = hn1;
      }
      hold0 = hn0; hold1 = hn1;
    }
    __syncthreads();           // all waves: s_waitcnt vmcnt(0) before s_barrier -> h stores at LLC
    if (tid == 0 && t < S_-1){
      __hip_atomic_store(gflag + ub, t + 1, __ATOMIC_RELAXED, __HIP_MEMORY_SCOPE_SYSTEM);
    }
    // hseq store AFTER the flag: no in-kernel consumer, keep it out of the drain
    if (tid < 256)
      *(unsigned*)(hseq_p + (size_t)tp * 2048) = pk;
  }
}

// ---------------- logits GEMM ----------------
__global__ void __launch_bounds__(256)
k_logits(const unsigned short* __restrict__ hseq, const unsigned short* __restrict__ wdT,
         const float* __restrict__ bd, float* __restrict__ out){
  __shared__ unsigned short As[128][40];
  int tid = threadIdx.x, w = tid >> 6, lane = tid & 63;
  size_t r0 = (size_t)blockIdx.x * 128;
  f32x4 acc[2][6];
  #pragma unroll
  for (int mt=0; mt<2; mt++)
    #pragma unroll
    for (int n=0; n<6; n++) acc[mt][n] = (f32x4){0.f,0.f,0.f,0.f};
  float bdv[6];
  #pragma unroll
  for (int n=0; n<6; n++) bdv[n] = bd[n*16 + (lane & 15)];

  for (int kc = 0; kc < 64; kc++){
    __syncthreads();
    #pragma unroll
    for (int i = 0; i < 2; i++){
      int v = tid*2 + i; int rr = v >> 2, k8 = (v & 3)*8;
      *(bf16x8*)&As[rr][k8] = *(const bf16x8*)(hseq + (r0 + rr)*2048 + kc*32 + k8);
    }
    __syncthreads();
    bf16x8 bfr[6];
    #pragma unroll
    for (int n=0; n<6; n++)
      bfr[n] = *(const bf16x8*)(wdT + (size_t)(n*16 + (lane&15))*2048 + kc*32 + (lane>>4)*8);
    #pragma unroll
    for (int mt=0; mt<2; mt++){
      bf16x8 a = *(const bf16x8*)&As[w*32 + mt*16 + (lane & 15)][(lane >> 4)*8];
      #pragma unroll
      for (int n=0; n<6; n++)
        acc[mt][n] = __builtin_amdgcn_mfma_f32_16x16x32_bf16(a, bfr[n], acc[mt][n], 0,0,0);
    }
  }
  #pragma unroll
  for (int mt=0; mt<2; mt++)
    #pragma unroll
    for (int n=0; n<6; n++)
      #pragma unroll
      for (int r4=0; r4<4; r4++){
        size_t row = r0 + w*32 + mt*16 + (lane>>4)*4 + r4;
        out[row*V_ + n*16 + (lane&15)] = acc[mt][n][r4] + bdv[n];
      }
}

// ---------------- launch ----------------
extern "C" void kernel_launch(void* const* d_in, const int* in_sizes, int n_in,
                              void* d_out, int out_size, void* d_ws, size_t ws_size,
                              hipStream_t stream){
  const int*   tok = (const int*)d_in[0];
  const float* emb = (const float*)d_in[1];
  const float* Wf  = (const float*)d_in[2];
  const float* Uf  = (const float*)d_in[3];
  const float* bf_ = (const float*)d_in[4];
  const float* Wb  = (const float*)d_in[5];
  const float* Ub  = (const float*)d_in[6];
  const float* bb_ = (const float*)d_in[7];
  const float* Wd  = (const float*)d_in[8];
  const float* bd  = (const float*)d_in[9];
  const float* h0f = (const float*)d_in[10];
  const float* h0b = (const float*)d_in[11];

  char* ws = (char*)d_ws;
  size_t off = 0;
  auto alloc = [&](size_t n){ char* p = ws + off; off += (n + 255) & ~(size_t)255; return p; };
  unsigned short* bp   = (unsigned short*)alloc((size_t)2*32*4*10*6*64*16);
  unsigned short* x    = (unsigned short*)alloc((size_t)B_*S_*E_*2);
  unsigned short* hseq = (unsigned short*)alloc((size_t)B_*S_*2048*2);
  unsigned short* hbuf = (unsigned short*)alloc((size_t)2*2*B_*U_*2);
  unsigned short* wdT  = (unsigned short*)alloc((size_t)V_*2048*2);
  float* comb = (float*)alloc((size_t)2*2048*4);
  float* bh0  = (float*)alloc((size_t)2*1024*4);
  float* bh1  = (float*)alloc((size_t)2*1024*4);
  int*   flags= (int*)alloc((size_t)1024*4);

  hipMemsetAsync(flags, 0, (size_t)1024*4, stream);
  k_embed<<<(B_*S_*E_+255)/256, 256, 0, stream>>>(tok, emb, x);
  k_hinit<<<(2*B_*U_+255)/256, 256, 0, stream>>>(h0f, h0b, hbuf);
  k_bias <<<(2*G3+255)/256, 256, 0, stream>>>(bf_, bb_, comb, bh0, bh1);
  k_wdt  <<<(V_*2048+255)/256, 256, 0, stream>>>(Wd, wdT);
  k_bpack<<<(2*32*4*10*6*64+255)/256, 256, 0, stream>>>(Uf, Wf, Ub, Wb, bp);
  k_rec  <<<256, 512, 0, stream>>>(bp, x, hbuf, hseq, comb, bh0, bh1, h0f, h0b, (float*)d_out, flags);
  k_logits<<<256, 256, 0, stream>>>(hseq, wdT, bd, (float*)d_out);
}